// Round 9
// baseline (623.227 us; speedup 1.0000x reference)
//
#include <hip/hip_runtime.h>
#include <math.h>

#define PI_F 3.14159265358979323846f
#define WAVES 8
#define TPB (WAVES*64)
#define TPB2 512

// gate pre-activation scales folded into weights at pack time:
// i,f,o rows: -log2(e); g rows: -2*log2(e)
#define GS_IFO (-1.4426950408889634f)
#define GS_G   (-2.8853900817779268f)

typedef _Float16 half_t;
typedef __attribute__((ext_vector_type(8))) _Float16 f16x8;
typedef __attribute__((ext_vector_type(4))) float f32x4;

union F16x8U { f16x8 v; unsigned int u[4]; half_t h[8]; };

__device__ __forceinline__ float frcp(float x)  { return __builtin_amdgcn_rcpf(x); }
__device__ __forceinline__ float fexp2(float x) { return __builtin_amdgcn_exp2f(x); }
__device__ __forceinline__ float ftanh(float x) { return 1.0f - 2.0f * frcp(1.0f + __expf(2.0f * x)); }

// gate with PRE-SCALED inputs: ai,af,ao = -log2e*orig ; ag = -2log2e*orig
__device__ __forceinline__ float2 lstm_gate(float ai, float af, float ag, float ao, float cold) {
    float ui = fexp2(ai);
    float uf = fexp2(af);
    float ug = fexp2(ag);
    float uo = fexp2(ao);
    float ig = (1.0f - ug) * frcp((1.0f + ui) * (1.0f + ug));   // sigmoid(i)*tanh(g)
    float ff = frcp(1.0f + uf);                                  // sigmoid(f)
    float cv = fmaf(ff, cold, ig);
    float uc = fexp2(GS_G * cv);
    float hh = (1.0f - uc) * frcp((1.0f + uo) * (1.0f + uc));   // sigmoid(o)*tanh(c)
    return make_float2(cv, hh);
}

#define MFMA16(a,b,c) __builtin_amdgcn_mfma_f32_16x16x32_f16((a),(b),(c),0,0,0)

// ---- d_ws layout (byte offsets) ----
#define AUG_B   98304
#define B1_B    99328
#define EPI_H   50176      // half index
#define BIAS_B  172032
#define HOUT_H  88064      // half index
#define EF_FUS  0
#define EF_R1   6144
#define EF_R2   18432
#define EF_HW1  30720
#define EF_HW2  34816

// ==================== K0: pack all weights ====================
__global__ void pack_weights(const float* __restrict__ w_ih0, const float* __restrict__ w_hh0, const float* __restrict__ b0,
                             const float* __restrict__ w_ih1, const float* __restrict__ w_hh1, const float* __restrict__ b1,
                             const float* __restrict__ fus_w, const float* __restrict__ fus_b,
                             const float* __restrict__ res_w1, const float* __restrict__ res_b1,
                             const float* __restrict__ res_w2, const float* __restrict__ res_b2,
                             const float* __restrict__ head_w1, const float* __restrict__ head_b1,
                             const float* __restrict__ head_w2, const float* __restrict__ head_b2,
                             half_t* __restrict__ hws)
{
    int id = blockIdx.x * blockDim.x + threadIdx.x;

    if (id < 6144) {                       // recurrent B-frags, gate-scaled
        int ln = id & 63, rest = id >> 6;
        int kb = rest & 1, cb = (rest >> 1) & 15, mat = rest >> 5;
        const float* W = (mat == 0) ? w_hh0 : ((mat == 1) ? w_ih1 : w_hh1);
        const int gate = cb >> 2;
        const float sc = (gate == 2) ? GS_G : GS_IFO;
        const float* src = W + (cb * 16 + (ln & 15)) * 64 + kb * 32 + (ln >> 4) * 8;
        F16x8U t;
        #pragma unroll
        for (int i = 0; i < 8; ++i) t.h[i] = (half_t)(sc * src[i]);
        *(f16x8*)&hws[id * 8] = t.v;
        return;
    }
    id -= 6144;
    if (id < 256) {                        // aug0 table: {w_ih0[j], b0[j]} gate-scaled
        const int gate = id >> 6;
        const float sc = (gate == 2) ? GS_G : GS_IFO;
        F16x8U t; t.u[0] = 0;
        t.h[0] = (half_t)(sc * w_ih0[id]);
        t.h[1] = (half_t)(sc * b0[id]);
        ((unsigned int*)((char*)hws + AUG_B))[id] = t.u[0];
        return;
    }
    id -= 256;
    if (id < 256) {                        // b1 fp32, gate-scaled
        const int gate = id >> 6;
        const float sc = (gate == 2) ? GS_G : GS_IFO;
        ((float*)((char*)hws + B1_B))[id] = sc * b1[id];
        return;
    }
    id -= 256;
    if (id < 768) {                        // fus frags (unscaled)
        int ln = id & 63, rest = id >> 6;
        int kb = rest % 3, cb = rest / 3;
        int col = cb * 16 + (ln & 15), q = ln >> 4;
        F16x8U t; t.u[0] = t.u[1] = t.u[2] = t.u[3] = 0;
        if (kb < 2) {
            #pragma unroll
            for (int i = 0; i < 8; ++i) t.h[i] = (half_t)fus_w[col * 66 + kb * 32 + q * 8 + i];
        } else if (q == 0) {
            t.h[0] = (half_t)fus_w[col * 66 + 64];
            t.h[1] = (half_t)fus_w[col * 66 + 65];
            t.h[2] = (half_t)fus_b[col];
        }
        *(f16x8*)&hws[(EPI_H + EF_FUS + id * 8)] = t.v;
        return;
    }
    id -= 768;
    if (id < 1536) {                       // res1 frags
        int ln = id & 63, rest = id >> 6;
        int kb = rest & 1, cb = (rest >> 1) & 3, rb = rest >> 3;
        int col = cb * 16 + (ln & 15), q = ln >> 4;
        F16x8U t;
        #pragma unroll
        for (int i = 0; i < 8; ++i) t.h[i] = (half_t)res_w1[rb * 4096 + col * 64 + kb * 32 + q * 8 + i];
        *(f16x8*)&hws[(EPI_H + EF_R1 + id * 8)] = t.v;
        return;
    }
    id -= 1536;
    if (id < 1536) {                       // res2 frags
        int ln = id & 63, rest = id >> 6;
        int kb = rest & 1, cb = (rest >> 1) & 3, rb = rest >> 3;
        int col = cb * 16 + (ln & 15), q = ln >> 4;
        F16x8U t;
        #pragma unroll
        for (int i = 0; i < 8; ++i) t.h[i] = (half_t)res_w2[rb * 4096 + col * 64 + kb * 32 + q * 8 + i];
        *(f16x8*)&hws[(EPI_H + EF_R2 + id * 8)] = t.v;
        return;
    }
    id -= 1536;
    if (id < 512) {                        // head_w1 frags
        int ln = id & 63, rest = id >> 6;
        int kb = rest & 1, cb = rest >> 1;
        int col = cb * 16 + (ln & 15), q = ln >> 4;
        F16x8U t;
        #pragma unroll
        for (int i = 0; i < 8; ++i) t.h[i] = (half_t)head_w1[col * 64 + kb * 32 + q * 8 + i];
        *(f16x8*)&hws[(EPI_H + EF_HW1 + id * 8)] = t.v;
        return;
    }
    id -= 512;
    if (id < 128) {                        // head_w2 frags
        int ln = id & 63, kb = id >> 6;
        int col = ln & 15, q = ln >> 4;
        F16x8U t; t.u[0] = t.u[1] = t.u[2] = t.u[3] = 0;
        if (col < 5) {
            #pragma unroll
            for (int i = 0; i < 8; ++i) t.h[i] = (half_t)head_w2[col * 64 + kb * 32 + q * 8 + i];
        }
        *(f16x8*)&hws[(EPI_H + EF_HW2 + id * 8)] = t.v;
        return;
    }
    id -= 128;
    if (id < 517) {                        // biases fp32 (unscaled, epilogue)
        float v;
        if      (id < 64)  v = fus_b[id];
        else if (id < 256) v = res_b1[id - 64];
        else if (id < 448) v = res_b2[id - 256];
        else if (id < 512) v = head_b1[id - 448];
        else               v = head_b2[id - 512];
        ((float*)((char*)hws + BIAS_B))[id] = v;
        return;
    }
}

// ==================== K1: LSTM main loop (2 tiles/wave, w_hh0 in regs) ====================
// launch_bounds(512, 2): VGPR cap 256 (est. peak ~228). Occupancy is LDS-bound at
// 8 waves/CU regardless of regs up to 256, so w_hh0's 128 regs are "free".
__global__ __launch_bounds__(TPB, 2)
void lstm_core(const float* __restrict__ xy, const half_t* __restrict__ hws, int N)
{
    __shared__ __align__(16) half_t wlds[2][16][2][64][8];          // w_ih1, w_hh1: 65536 B
    __shared__ __align__(16) half_t hfrag[WAVES][2][2][2][64][8];   // 65536 B
    __shared__ unsigned int aug_lds[256];                           // 1 KB
    __shared__ float b1_lds[256];                                   // 1 KB -> 133120 B total

    const int lane = threadIdx.x & 63;
    const int wid  = threadIdx.x >> 6;
    const int cc   = lane & 15;
    const int qq   = lane >> 4;

    // stage layer-1 weights into LDS (mats 1,2 of the packed frags)
    for (int idx = threadIdx.x; idx < 4096; idx += TPB)
        *(f16x8*)&((half_t*)wlds)[idx * 8] = *(const f16x8*)&hws[(2048 + idx) * 8];
    if (threadIdx.x < 256) {
        aug_lds[threadIdx.x] = ((const unsigned int*)((const char*)hws + AUG_B))[threadIdx.x];
        b1_lds[threadIdx.x]  = ((const float*)((const char*)hws + B1_B))[threadIdx.x];
    }

    // w_hh0 B-frags register-resident (32 x f16x8 = 128 VGPR; L2-hit, once per wave)
    f16x8 wh0[16][2];
    #pragma unroll
    for (int cb = 0; cb < 16; ++cb) {
        wh0[cb][0] = *(const f16x8*)&hws[((cb * 2 + 0) * 64 + lane) * 8];
        wh0[cb][1] = *(const f16x8*)&hws[((cb * 2 + 1) * 64 + lane) * 8];
    }
    __syncthreads();

    const int pair = blockIdx.x * WAVES + wid;    // each wave: tiles 2p, 2p+1 (32 samples)
    const int S0 = pair * 32;
    if (S0 >= N) return;

    int si0 = S0 + cc;      if (si0 >= N) si0 = N - 1;
    int si1 = S0 + 16 + cc; if (si1 >= N) si1 = N - 1;
    const float fx0 = xy[2 * si0], fy0 = xy[2 * si0 + 1];
    const float fx1 = xy[2 * si1], fy1 = xy[2 * si1 + 1];
    float feat0[9], feat1[9];
    feat0[0] = fx0; feat0[1] = fy0; feat0[2] = fx0 * fx0; feat0[3] = fy0 * fy0; feat0[4] = fx0 * fy0;
    feat0[5] = sinf(PI_F * fx0); feat0[6] = cosf(PI_F * fx0);
    feat0[7] = sinf(PI_F * fy0); feat0[8] = cosf(PI_F * fy0);
    feat1[0] = fx1; feat1[1] = fy1; feat1[2] = fx1 * fx1; feat1[3] = fy1 * fy1; feat1[4] = fx1 * fy1;
    feat1[5] = sinf(PI_F * fx1); feat1[6] = cosf(PI_F * fx1);
    feat1[7] = sinf(PI_F * fy1); feat1[8] = cosf(PI_F * fy1);

    {
        F16x8U Z; Z.u[0] = Z.u[1] = Z.u[2] = Z.u[3] = 0;
        #pragma unroll
        for (int p = 0; p < 2; ++p)
            #pragma unroll
            for (int b = 0; b < 2; ++b)
                #pragma unroll
                for (int kb = 0; kb < 2; ++kb)
                    *(f16x8*)&hfrag[wid][p][b][kb][lane][0] = Z.v;
    }
    float c0s[2][4][4], c1s[2][4][4];
    #pragma unroll
    for (int p = 0; p < 2; ++p)
        #pragma unroll
        for (int a = 0; a < 4; ++a)
            #pragma unroll
            for (int b = 0; b < 4; ++b) { c0s[p][a][b] = 0.0f; c1s[p][a][b] = 0.0f; }

    asm volatile("" ::: "memory");   // one fence after init; per-phase ordering is
                                     // compiler-visible through the hfrag array itself

    #pragma unroll 1
    for (int t = 0; t < 9; ++t) {
        float ftv0, ftv1;
        switch (t) {
            case 0: ftv0 = feat0[0]; ftv1 = feat1[0]; break;
            case 1: ftv0 = feat0[1]; ftv1 = feat1[1]; break;
            case 2: ftv0 = feat0[2]; ftv1 = feat1[2]; break;
            case 3: ftv0 = feat0[3]; ftv1 = feat1[3]; break;
            case 4: ftv0 = feat0[4]; ftv1 = feat1[4]; break;
            case 5: ftv0 = feat0[5]; ftv1 = feat1[5]; break;
            case 6: ftv0 = feat0[6]; ftv1 = feat1[6]; break;
            case 7: ftv0 = feat0[7]; ftv1 = feat1[7]; break;
            default: ftv0 = feat0[8]; ftv1 = feat1[8]; break;
        }
        F16x8U AG0, AG1;
        AG0.u[0] = AG0.u[1] = AG0.u[2] = AG0.u[3] = 0;
        AG1.u[0] = AG1.u[1] = AG1.u[2] = AG1.u[3] = 0;
        if (qq == 0) {
            AG0.h[0] = (half_t)ftv0; AG0.h[1] = (half_t)1.0f;
            AG1.h[0] = (half_t)ftv1; AG1.h[1] = (half_t)1.0f;
        }

        // h1 A-frags from previous step (independent of this step's layer 0):
        f16x8 q0b0 = *(const f16x8*)&hfrag[wid][0][1][0][lane][0];
        f16x8 q0b1 = *(const f16x8*)&hfrag[wid][0][1][1][lane][0];
        f16x8 q1b0 = *(const f16x8*)&hfrag[wid][1][1][0][lane][0];
        f16x8 q1b1 = *(const f16x8*)&hfrag[wid][1][1][1][lane][0];

        // ------- layer 0 (B-frags from registers) -------
        f16x8 p0a0 = *(const f16x8*)&hfrag[wid][0][0][0][lane][0];
        f16x8 p0a1 = *(const f16x8*)&hfrag[wid][0][0][1][lane][0];
        f16x8 p1a0 = *(const f16x8*)&hfrag[wid][1][0][0][lane][0];
        f16x8 p1a1 = *(const f16x8*)&hfrag[wid][1][0][1][lane][0];
        #pragma unroll
        for (int jj = 0; jj < 4; ++jj) {
            f32x4 acc0[4], acc1[4];
            #pragma unroll
            for (int g = 0; g < 4; ++g) {
                const int cb = jj + 4 * g;
                F16x8U BA; BA.u[0] = (qq == 0) ? aug_lds[cb * 16 + cc] : 0u;
                BA.u[1] = 0; BA.u[2] = 0; BA.u[3] = 0;
                f32x4 a0 = {0.f, 0.f, 0.f, 0.f};
                a0 = MFMA16(AG0.v, BA.v, a0);
                a0 = MFMA16(p0a0, wh0[cb][0], a0);
                a0 = MFMA16(p0a1, wh0[cb][1], a0);
                acc0[g] = a0;
                f32x4 a1 = {0.f, 0.f, 0.f, 0.f};
                a1 = MFMA16(AG1.v, BA.v, a1);
                a1 = MFMA16(p1a0, wh0[cb][0], a1);
                a1 = MFMA16(p1a1, wh0[cb][1], a1);
                acc1[g] = a1;
            }
            const int kb = jj >> 1;
            const int lb = (4 * qq + 16 * ((2 * jj + (cc >> 3)) & 3)) * 8 + (cc & 7);
            half_t* hp0 = &hfrag[wid][0][0][kb][0][0];
            half_t* hp1 = &hfrag[wid][1][0][kb][0][0];
            #pragma unroll
            for (int r = 0; r < 4; ++r) {
                float2 ch0 = lstm_gate(acc0[0][r], acc0[1][r], acc0[2][r], acc0[3][r], c0s[0][jj][r]);
                c0s[0][jj][r] = ch0.x;
                hp0[lb + 8 * r] = (half_t)ch0.y;
                float2 ch1 = lstm_gate(acc1[0][r], acc1[1][r], acc1[2][r], acc1[3][r], c0s[1][jj][r]);
                c0s[1][jj][r] = ch1.x;
                hp1[lb + 8 * r] = (half_t)ch1.y;
            }
        }

        // ------- layer 1 (h1-recurrent MFMAs first: independent of layer-0 gates) -------
        f16x8 q0a0 = *(const f16x8*)&hfrag[wid][0][0][0][lane][0];
        f16x8 q0a1 = *(const f16x8*)&hfrag[wid][0][0][1][lane][0];
        f16x8 q1a0 = *(const f16x8*)&hfrag[wid][1][0][0][lane][0];
        f16x8 q1a1 = *(const f16x8*)&hfrag[wid][1][0][1][lane][0];
        #pragma unroll
        for (int jj = 0; jj < 4; ++jj) {
            f32x4 acc0[4], acc1[4];
            #pragma unroll
            for (int g = 0; g < 4; ++g) {
                const int cb = jj + 4 * g;
                const float bv = b1_lds[cb * 16 + cc];
                f16x8 bi0 = *(const f16x8*)&wlds[0][cb][0][lane][0];
                f16x8 bi1 = *(const f16x8*)&wlds[0][cb][1][lane][0];
                f16x8 bh0 = *(const f16x8*)&wlds[1][cb][0][lane][0];
                f16x8 bh1 = *(const f16x8*)&wlds[1][cb][1][lane][0];
                f32x4 a0 = {bv, bv, bv, bv};
                a0 = MFMA16(q0b0, bh0, a0);     // h1 part first (indep of L0 gates)
                a0 = MFMA16(q0b1, bh1, a0);
                a0 = MFMA16(q0a0, bi0, a0);     // h0 part (dep on L0 gates)
                a0 = MFMA16(q0a1, bi1, a0);
                acc0[g] = a0;
                f32x4 a1 = {bv, bv, bv, bv};
                a1 = MFMA16(q1b0, bh0, a1);
                a1 = MFMA16(q1b1, bh1, a1);
                a1 = MFMA16(q1a0, bi0, a1);
                a1 = MFMA16(q1a1, bi1, a1);
                acc1[g] = a1;
            }
            const int kb = jj >> 1;
            const int lb = (4 * qq + 16 * ((2 * jj + (cc >> 3)) & 3)) * 8 + (cc & 7);
            half_t* hp0 = &hfrag[wid][0][1][kb][0][0];
            half_t* hp1 = &hfrag[wid][1][1][kb][0][0];
            #pragma unroll
            for (int r = 0; r < 4; ++r) {
                float2 ch0 = lstm_gate(acc0[0][r], acc0[1][r], acc0[2][r], acc0[3][r], c1s[0][jj][r]);
                c1s[0][jj][r] = ch0.x;
                hp0[lb + 8 * r] = (half_t)ch0.y;
                float2 ch1 = lstm_gate(acc1[0][r], acc1[1][r], acc1[2][r], acc1[3][r], c1s[1][jj][r]);
                c1s[1][jj][r] = ch1.x;
                hp1[lb + 8 * r] = (half_t)ch1.y;
            }
        }
    }

    // store final h1 A-frags for both tiles
    const int ntiles = (N + 15) >> 4;
    {
        const int tile0 = pair * 2;
        half_t* hout = (half_t*)hws + HOUT_H + (size_t)tile0 * 1024;
        *(f16x8*)&hout[0   + lane * 8] = *(const f16x8*)&hfrag[wid][0][1][0][lane][0];
        *(f16x8*)&hout[512 + lane * 8] = *(const f16x8*)&hfrag[wid][0][1][1][lane][0];
        if (tile0 + 1 < ntiles) {
            half_t* hout1 = (half_t*)hws + HOUT_H + (size_t)(tile0 + 1) * 1024;
            *(f16x8*)&hout1[0   + lane * 8] = *(const f16x8*)&hfrag[wid][1][1][0][lane][0];
            *(f16x8*)&hout1[512 + lane * 8] = *(const f16x8*)&hfrag[wid][1][1][1][lane][0];
        }
    }
}

// ==================== K2: epilogue MLP ====================
__global__ __launch_bounds__(TPB2, 1)
void epi_mlp(const float* __restrict__ xy, const half_t* __restrict__ hws,
             float* __restrict__ out, int ntiles, int N)
{
    __shared__ __align__(16) half_t ef[35840];                  // 70 KB
    __shared__ float biasl[517];
    __shared__ __align__(16) half_t hbuf[8][2][2][64][8];       // 32 KB

    for (int idx = threadIdx.x; idx < 4480; idx += TPB2)
        *(f16x8*)&ef[idx * 8] = *(const f16x8*)&hws[(EPI_H + idx * 8)];
    const float* bg = (const float*)((const char*)hws + BIAS_B);
    for (int i = threadIdx.x; i < 517; i += TPB2) biasl[i] = bg[i];
    __syncthreads();

    const half_t* hout = hws + HOUT_H;
    const int lane = threadIdx.x & 63;
    const int wid  = threadIdx.x >> 6;
    const int cc   = lane & 15;
    const int qq   = lane >> 4;
    const int gw = blockIdx.x * 8 + wid;
    const int nw = gridDim.x * 8;

#define WRITE_ACT(BUF, VALS) do {                                              \
        _Pragma("unroll")                                                      \
        for (int cb = 0; cb < 4; ++cb) {                                       \
            half_t* hp = &hbuf[wid][BUF][cb >> 1][0][0];                       \
            const int lb = (4*qq + 16*((2*cb + (cc>>3)) & 3))*8 + (cc & 7);    \
            _Pragma("unroll")                                                  \
            for (int r = 0; r < 4; ++r) hp[lb + 8*r] = (half_t)(VALS)[cb][r];  \
        }                                                                      \
        asm volatile("" ::: "memory");                                         \
    } while (0)

    #pragma unroll 1
    for (int tile = gw; tile < ntiles; tile += nw) {
        const size_t hob = (size_t)tile * 1024;
        f16x8 e0 = *(const f16x8*)&hout[hob + lane * 8];
        f16x8 e1 = *(const f16x8*)&hout[hob + 512 + lane * 8];

        int s = tile * 16 + cc; if (s >= N) s = N - 1;
        const float fx = xy[2 * s], fy = xy[2 * s + 1];
        F16x8U AF; AF.u[0] = AF.u[1] = AF.u[2] = AF.u[3] = 0;
        if (qq == 0) { AF.h[0] = (half_t)fx; AF.h[1] = (half_t)fy; AF.h[2] = (half_t)1.0f; }

        float zz[4][4];
        #pragma unroll
        for (int cb = 0; cb < 4; ++cb) {
            f32x4 a = {0.f, 0.f, 0.f, 0.f};
            a = MFMA16(e0,   *(const f16x8*)&ef[(EF_FUS + ((cb * 3 + 0) * 64 + lane) * 8)], a);
            a = MFMA16(e1,   *(const f16x8*)&ef[(EF_FUS + ((cb * 3 + 1) * 64 + lane) * 8)], a);
            a = MFMA16(AF.v, *(const f16x8*)&ef[(EF_FUS + ((cb * 3 + 2) * 64 + lane) * 8)], a);
            #pragma unroll
            for (int r = 0; r < 4; ++r) zz[cb][r] = ftanh(a[r]);
        }
        WRITE_ACT(0, zz);
        f16x8 za0 = *(const f16x8*)&hbuf[wid][0][0][lane][0];
        f16x8 za1 = *(const f16x8*)&hbuf[wid][0][1][lane][0];

        #pragma unroll 1
        for (int rb = 0; rb < 3; ++rb) {
            float tt[4][4];
            #pragma unroll
            for (int cb = 0; cb < 4; ++cb) {
                const float bv = biasl[64 + rb * 64 + cb * 16 + cc];
                f32x4 a = {bv, bv, bv, bv};
                a = MFMA16(za0, *(const f16x8*)&ef[(EF_R1 + (((rb * 4 + cb) * 2 + 0) * 64 + lane) * 8)], a);
                a = MFMA16(za1, *(const f16x8*)&ef[(EF_R1 + (((rb * 4 + cb) * 2 + 1) * 64 + lane) * 8)], a);
                #pragma unroll
                for (int r = 0; r < 4; ++r) tt[cb][r] = ftanh(a[r]);
            }
            WRITE_ACT(1, tt);
            f16x8 ta0 = *(const f16x8*)&hbuf[wid][1][0][lane][0];
            f16x8 ta1 = *(const f16x8*)&hbuf[wid][1][1][lane][0];
            #pragma unroll
            for (int cb = 0; cb < 4; ++cb) {
                const float bv = biasl[256 + rb * 64 + cb * 16 + cc];
                f32x4 a = {bv, bv, bv, bv};
                a = MFMA16(ta0, *(const f16x8*)&ef[(EF_R2 + (((rb * 4 + cb) * 2 + 0) * 64 + lane) * 8)], a);
                a = MFMA16(ta1, *(const f16x8*)&ef[(EF_R2 + (((rb * 4 + cb) * 2 + 1) * 64 + lane) * 8)], a);
                #pragma unroll
                for (int r = 0; r < 4; ++r) zz[cb][r] += ftanh(a[r]);
            }
            WRITE_ACT(0, zz);
            za0 = *(const f16x8*)&hbuf[wid][0][0][lane][0];
            za1 = *(const f16x8*)&hbuf[wid][0][1][lane][0];
        }

        float hh[4][4];
        #pragma unroll
        for (int cb = 0; cb < 4; ++cb) {
            const float bv = biasl[448 + cb * 16 + cc];
            f32x4 a = {bv, bv, bv, bv};
            a = MFMA16(za0, *(const f16x8*)&ef[(EF_HW1 + ((cb * 2 + 0) * 64 + lane) * 8)], a);
            a = MFMA16(za1, *(const f16x8*)&ef[(EF_HW1 + ((cb * 2 + 1) * 64 + lane) * 8)], a);
            #pragma unroll
            for (int r = 0; r < 4; ++r) hh[cb][r] = ftanh(a[r]);
        }
        WRITE_ACT(1, hh);
        f16x8 ha0 = *(const f16x8*)&hbuf[wid][1][0][lane][0];
        f16x8 ha1 = *(const f16x8*)&hbuf[wid][1][1][lane][0];

        {
            const float bv = (cc < 5) ? biasl[512 + cc] : 0.0f;
            f32x4 a = {bv, bv, bv, bv};
            a = MFMA16(ha0, *(const f16x8*)&ef[(EF_HW2 + ((0) * 64 + lane) * 8)], a);
            a = MFMA16(ha1, *(const f16x8*)&ef[(EF_HW2 + ((1) * 64 + lane) * 8)], a);
            if (cc < 5) {
                #pragma unroll
                for (int r = 0; r < 4; ++r) {
                    const int row = tile * 16 + 4 * qq + r;
                    if (row < N) out[row * 5 + cc] = a[r];
                }
            }
        }
    }
#undef WRITE_ACT
}

extern "C" void kernel_launch(void* const* d_in, const int* in_sizes, int n_in,
                              void* d_out, int out_size, void* d_ws, size_t ws_size,
                              hipStream_t stream) {
    const float* xy      = (const float*)d_in[0];
    const float* w_ih0   = (const float*)d_in[1];
    const float* w_hh0   = (const float*)d_in[2];
    const float* b0      = (const float*)d_in[3];
    const float* w_ih1   = (const float*)d_in[4];
    const float* w_hh1   = (const float*)d_in[5];
    const float* b1      = (const float*)d_in[6];
    const float* fus_w   = (const float*)d_in[7];
    const float* fus_b   = (const float*)d_in[8];
    const float* res_w1  = (const float*)d_in[9];
    const float* res_b1  = (const float*)d_in[10];
    const float* res_w2  = (const float*)d_in[11];
    const float* res_b2  = (const float*)d_in[12];
    const float* head_w1 = (const float*)d_in[13];
    const float* head_b1 = (const float*)d_in[14];
    const float* head_w2 = (const float*)d_in[15];
    const float* head_b2 = (const float*)d_in[16];

    const int N = in_sizes[0] / 2;
    const int ntiles = (N + 15) / 16;
    const int npairs = (ntiles + 1) / 2;
    half_t* hws = (half_t*)d_ws;

    pack_weights<<<dim3(46), dim3(256), 0, stream>>>(
        w_ih0, w_hh0, b0, w_ih1, w_hh1, b1,
        fus_w, fus_b, res_w1, res_b1, res_w2, res_b2,
        head_w1, head_b1, head_w2, head_b2, hws);

    const int grid1 = (npairs + WAVES - 1) / WAVES;
    lstm_core<<<dim3(grid1), dim3(TPB), 0, stream>>>(xy, hws, N);

    epi_mlp<<<dim3(256), dim3(TPB2), 0, stream>>>(xy, hws, (float*)d_out, ntiles, N);
}

// Round 10
// 529.674 us; speedup vs baseline: 1.1766x; 1.1766x over previous
//
#include <hip/hip_runtime.h>
#include <math.h>

#define PI_F 3.14159265358979323846f
#define WAVES 8
#define TPB (WAVES*64)
#define TPB2 512

// gate pre-activation scales folded into weights at pack time:
// i,f,o rows: -log2(e); g rows: -2*log2(e)
#define GS_IFO (-1.4426950408889634f)
#define GS_G   (-2.8853900817779268f)

typedef _Float16 half_t;
typedef __attribute__((ext_vector_type(8))) _Float16 f16x8;
typedef __attribute__((ext_vector_type(4))) float f32x4;

union F16x8U { f16x8 v; unsigned int u[4]; half_t h[8]; };

__device__ __forceinline__ float frcp(float x)  { return __builtin_amdgcn_rcpf(x); }
__device__ __forceinline__ float fexp2(float x) { return __builtin_amdgcn_exp2f(x); }
__device__ __forceinline__ float ftanh(float x) { return 1.0f - 2.0f * frcp(1.0f + __expf(2.0f * x)); }

// gate with PRE-SCALED inputs: ai,af,ao = -log2e*orig ; ag = -2log2e*orig
__device__ __forceinline__ float2 lstm_gate(float ai, float af, float ag, float ao, float cold) {
    float ui = fexp2(ai);
    float uf = fexp2(af);
    float ug = fexp2(ag);
    float uo = fexp2(ao);
    float ig = (1.0f - ug) * frcp((1.0f + ui) * (1.0f + ug));   // sigmoid(i)*tanh(g)
    float ff = frcp(1.0f + uf);                                  // sigmoid(f)
    float cv = fmaf(ff, cold, ig);
    float uc = fexp2(GS_G * cv);
    float hh = (1.0f - uc) * frcp((1.0f + uo) * (1.0f + uc));   // sigmoid(o)*tanh(c)
    return make_float2(cv, hh);
}

#define MFMA16(a,b,c) __builtin_amdgcn_mfma_f32_16x16x32_f16((a),(b),(c),0,0,0)

// ---- d_ws layout (byte offsets) ----
#define AUG_B   98304
#define B1_B    99328
#define EPI_H   50176      // half index
#define BIAS_B  172032
#define HOUT_H  88064      // half index
#define EF_FUS  0
#define EF_R1   6144
#define EF_R2   18432
#define EF_HW1  30720
#define EF_HW2  34816

// ==================== K0: pack all weights ====================
__global__ void pack_weights(const float* __restrict__ w_ih0, const float* __restrict__ w_hh0, const float* __restrict__ b0,
                             const float* __restrict__ w_ih1, const float* __restrict__ w_hh1, const float* __restrict__ b1,
                             const float* __restrict__ fus_w, const float* __restrict__ fus_b,
                             const float* __restrict__ res_w1, const float* __restrict__ res_b1,
                             const float* __restrict__ res_w2, const float* __restrict__ res_b2,
                             const float* __restrict__ head_w1, const float* __restrict__ head_b1,
                             const float* __restrict__ head_w2, const float* __restrict__ head_b2,
                             half_t* __restrict__ hws)
{
    int id = blockIdx.x * blockDim.x + threadIdx.x;

    if (id < 6144) {                       // recurrent B-frags, gate-scaled
        int ln = id & 63, rest = id >> 6;
        int kb = rest & 1, cb = (rest >> 1) & 15, mat = rest >> 5;
        const float* W = (mat == 0) ? w_hh0 : ((mat == 1) ? w_ih1 : w_hh1);
        const int gate = cb >> 2;
        const float sc = (gate == 2) ? GS_G : GS_IFO;
        const float* src = W + (cb * 16 + (ln & 15)) * 64 + kb * 32 + (ln >> 4) * 8;
        F16x8U t;
        #pragma unroll
        for (int i = 0; i < 8; ++i) t.h[i] = (half_t)(sc * src[i]);
        *(f16x8*)&hws[id * 8] = t.v;
        return;
    }
    id -= 6144;
    if (id < 256) {                        // aug0 table: {w_ih0[j], b0[j]} gate-scaled
        const int gate = id >> 6;
        const float sc = (gate == 2) ? GS_G : GS_IFO;
        F16x8U t; t.u[0] = 0;
        t.h[0] = (half_t)(sc * w_ih0[id]);
        t.h[1] = (half_t)(sc * b0[id]);
        ((unsigned int*)((char*)hws + AUG_B))[id] = t.u[0];
        return;
    }
    id -= 256;
    if (id < 256) {                        // b1 fp32, gate-scaled
        const int gate = id >> 6;
        const float sc = (gate == 2) ? GS_G : GS_IFO;
        ((float*)((char*)hws + B1_B))[id] = sc * b1[id];
        return;
    }
    id -= 256;
    if (id < 768) {                        // fus frags (unscaled)
        int ln = id & 63, rest = id >> 6;
        int kb = rest % 3, cb = rest / 3;
        int col = cb * 16 + (ln & 15), q = ln >> 4;
        F16x8U t; t.u[0] = t.u[1] = t.u[2] = t.u[3] = 0;
        if (kb < 2) {
            #pragma unroll
            for (int i = 0; i < 8; ++i) t.h[i] = (half_t)fus_w[col * 66 + kb * 32 + q * 8 + i];
        } else if (q == 0) {
            t.h[0] = (half_t)fus_w[col * 66 + 64];
            t.h[1] = (half_t)fus_w[col * 66 + 65];
            t.h[2] = (half_t)fus_b[col];
        }
        *(f16x8*)&hws[(EPI_H + EF_FUS + id * 8)] = t.v;
        return;
    }
    id -= 768;
    if (id < 1536) {                       // res1 frags
        int ln = id & 63, rest = id >> 6;
        int kb = rest & 1, cb = (rest >> 1) & 3, rb = rest >> 3;
        int col = cb * 16 + (ln & 15), q = ln >> 4;
        F16x8U t;
        #pragma unroll
        for (int i = 0; i < 8; ++i) t.h[i] = (half_t)res_w1[rb * 4096 + col * 64 + kb * 32 + q * 8 + i];
        *(f16x8*)&hws[(EPI_H + EF_R1 + id * 8)] = t.v;
        return;
    }
    id -= 1536;
    if (id < 1536) {                       // res2 frags
        int ln = id & 63, rest = id >> 6;
        int kb = rest & 1, cb = (rest >> 1) & 3, rb = rest >> 3;
        int col = cb * 16 + (ln & 15), q = ln >> 4;
        F16x8U t;
        #pragma unroll
        for (int i = 0; i < 8; ++i) t.h[i] = (half_t)res_w2[rb * 4096 + col * 64 + kb * 32 + q * 8 + i];
        *(f16x8*)&hws[(EPI_H + EF_R2 + id * 8)] = t.v;
        return;
    }
    id -= 1536;
    if (id < 512) {                        // head_w1 frags
        int ln = id & 63, rest = id >> 6;
        int kb = rest & 1, cb = rest >> 1;
        int col = cb * 16 + (ln & 15), q = ln >> 4;
        F16x8U t;
        #pragma unroll
        for (int i = 0; i < 8; ++i) t.h[i] = (half_t)head_w1[col * 64 + kb * 32 + q * 8 + i];
        *(f16x8*)&hws[(EPI_H + EF_HW1 + id * 8)] = t.v;
        return;
    }
    id -= 512;
    if (id < 128) {                        // head_w2 frags
        int ln = id & 63, kb = id >> 6;
        int col = ln & 15, q = ln >> 4;
        F16x8U t; t.u[0] = t.u[1] = t.u[2] = t.u[3] = 0;
        if (col < 5) {
            #pragma unroll
            for (int i = 0; i < 8; ++i) t.h[i] = (half_t)head_w2[col * 64 + kb * 32 + q * 8 + i];
        }
        *(f16x8*)&hws[(EPI_H + EF_HW2 + id * 8)] = t.v;
        return;
    }
    id -= 128;
    if (id < 517) {                        // biases fp32 (unscaled, epilogue)
        float v;
        if      (id < 64)  v = fus_b[id];
        else if (id < 256) v = res_b1[id - 64];
        else if (id < 448) v = res_b2[id - 256];
        else if (id < 512) v = head_b1[id - 448];
        else               v = head_b2[id - 512];
        ((float*)((char*)hws + BIAS_B))[id] = v;
        return;
    }
}

// ==================== K1: LSTM main loop (2 tiles/wave, round-8 structure) ====================
// launch_bounds(512, 2). All three recurrent matrices in LDS (96 KB) + hfrag 64 KB = 160 KiB.
// NOTE (rounds 3/5/9): any plan needing >~128 live VGPRs spills — weights stay in LDS.
__global__ __launch_bounds__(TPB, 2)
void lstm_core(const float* __restrict__ xy, const half_t* __restrict__ hws, int N)
{
    __shared__ __align__(16) half_t wlds[3][16][2][64][8];          // 98304 B
    __shared__ __align__(16) half_t hfrag[WAVES][2][2][2][64][8];   // 65536 B -> 163840 total

    const int lane = threadIdx.x & 63;
    const int wid  = threadIdx.x >> 6;
    const int cc   = lane & 15;
    const int qq   = lane >> 4;

    // stage pre-packed weights (flat vector copy)
    for (int idx = threadIdx.x; idx < 6144; idx += TPB)
        *(f16x8*)&((half_t*)wlds)[idx * 8] = *(const f16x8*)&hws[idx * 8];
    __syncthreads();

    // loop-invariant per-lane tables in VGPRs (L2-hit loads, once)  [round-8 proven]
    unsigned int augr[16];
    float b1r[16];
    {
        const unsigned int* at = (const unsigned int*)((const char*)hws + AUG_B);
        const float* bt = (const float*)((const char*)hws + B1_B);
        #pragma unroll
        for (int cb = 0; cb < 16; ++cb) {
            augr[cb] = (qq == 0) ? at[cb * 16 + cc] : 0u;
            b1r[cb]  = bt[cb * 16 + cc];
        }
    }

    const int pair = blockIdx.x * WAVES + wid;    // each wave: tiles 2p, 2p+1 (32 samples)
    const int S0 = pair * 32;
    if (S0 >= N) return;

    int si0 = S0 + cc;      if (si0 >= N) si0 = N - 1;
    int si1 = S0 + 16 + cc; if (si1 >= N) si1 = N - 1;
    const float fx0 = xy[2 * si0], fy0 = xy[2 * si0 + 1];
    const float fx1 = xy[2 * si1], fy1 = xy[2 * si1 + 1];
    float feat0[9], feat1[9];
    feat0[0] = fx0; feat0[1] = fy0; feat0[2] = fx0 * fx0; feat0[3] = fy0 * fy0; feat0[4] = fx0 * fy0;
    feat0[5] = sinf(PI_F * fx0); feat0[6] = cosf(PI_F * fx0);
    feat0[7] = sinf(PI_F * fy0); feat0[8] = cosf(PI_F * fy0);
    feat1[0] = fx1; feat1[1] = fy1; feat1[2] = fx1 * fx1; feat1[3] = fy1 * fy1; feat1[4] = fx1 * fy1;
    feat1[5] = sinf(PI_F * fx1); feat1[6] = cosf(PI_F * fx1);
    feat1[7] = sinf(PI_F * fy1); feat1[8] = cosf(PI_F * fy1);

    {
        F16x8U Z; Z.u[0] = Z.u[1] = Z.u[2] = Z.u[3] = 0;
        #pragma unroll
        for (int p = 0; p < 2; ++p)
            #pragma unroll
            for (int b = 0; b < 2; ++b)
                #pragma unroll
                for (int kb = 0; kb < 2; ++kb)
                    *(f16x8*)&hfrag[wid][p][b][kb][lane][0] = Z.v;
    }
    float c0s[2][4][4], c1s[2][4][4];
    #pragma unroll
    for (int p = 0; p < 2; ++p)
        #pragma unroll
        for (int a = 0; a < 4; ++a)
            #pragma unroll
            for (int b = 0; b < 4; ++b) { c0s[p][a][b] = 0.0f; c1s[p][a][b] = 0.0f; }

    asm volatile("" ::: "memory");   // single fence after init (round-9-verified:
                                     // per-phase ordering is carried by hfrag aliasing)

    #pragma unroll 1
    for (int t = 0; t < 9; ++t) {
        float ftv0, ftv1;
        switch (t) {
            case 0: ftv0 = feat0[0]; ftv1 = feat1[0]; break;
            case 1: ftv0 = feat0[1]; ftv1 = feat1[1]; break;
            case 2: ftv0 = feat0[2]; ftv1 = feat1[2]; break;
            case 3: ftv0 = feat0[3]; ftv1 = feat1[3]; break;
            case 4: ftv0 = feat0[4]; ftv1 = feat1[4]; break;
            case 5: ftv0 = feat0[5]; ftv1 = feat1[5]; break;
            case 6: ftv0 = feat0[6]; ftv1 = feat1[6]; break;
            case 7: ftv0 = feat0[7]; ftv1 = feat1[7]; break;
            default: ftv0 = feat0[8]; ftv1 = feat1[8]; break;
        }
        F16x8U AG0, AG1;
        AG0.u[0] = AG0.u[1] = AG0.u[2] = AG0.u[3] = 0;
        AG1.u[0] = AG1.u[1] = AG1.u[2] = AG1.u[3] = 0;
        if (qq == 0) {
            AG0.h[0] = (half_t)ftv0; AG0.h[1] = (half_t)1.0f;
            AG1.h[0] = (half_t)ftv1; AG1.h[1] = (half_t)1.0f;
        }

        // prev-step h1 A-frags (independent of this step's layer 0) — read early
        f16x8 q0b0 = *(const f16x8*)&hfrag[wid][0][1][0][lane][0];
        f16x8 q0b1 = *(const f16x8*)&hfrag[wid][0][1][1][lane][0];
        f16x8 q1b0 = *(const f16x8*)&hfrag[wid][1][1][0][lane][0];
        f16x8 q1b1 = *(const f16x8*)&hfrag[wid][1][1][1][lane][0];

        // ------- layer 0 (both tiles share every B-frag read) -------
        f16x8 p0a0 = *(const f16x8*)&hfrag[wid][0][0][0][lane][0];
        f16x8 p0a1 = *(const f16x8*)&hfrag[wid][0][0][1][lane][0];
        f16x8 p1a0 = *(const f16x8*)&hfrag[wid][1][0][0][lane][0];
        f16x8 p1a1 = *(const f16x8*)&hfrag[wid][1][0][1][lane][0];
        #pragma unroll
        for (int jj = 0; jj < 4; ++jj) {
            f32x4 acc0[4], acc1[4];
            __builtin_amdgcn_s_setprio(1);
            #pragma unroll
            for (int g = 0; g < 4; ++g) {
                const int cb = jj + 4 * g;
                F16x8U BA; BA.u[0] = augr[cb]; BA.u[1] = 0; BA.u[2] = 0; BA.u[3] = 0;
                f16x8 bf0 = *(const f16x8*)&wlds[0][cb][0][lane][0];
                f16x8 bf1 = *(const f16x8*)&wlds[0][cb][1][lane][0];
                f32x4 a0 = {0.f, 0.f, 0.f, 0.f};
                a0 = MFMA16(AG0.v, BA.v, a0);
                a0 = MFMA16(p0a0, bf0, a0);
                a0 = MFMA16(p0a1, bf1, a0);
                acc0[g] = a0;
                f32x4 a1 = {0.f, 0.f, 0.f, 0.f};
                a1 = MFMA16(AG1.v, BA.v, a1);
                a1 = MFMA16(p1a0, bf0, a1);
                a1 = MFMA16(p1a1, bf1, a1);
                acc1[g] = a1;
            }
            __builtin_amdgcn_s_setprio(0);
            const int kb = jj >> 1;
            const int lb = (4 * qq + 16 * ((2 * jj + (cc >> 3)) & 3)) * 8 + (cc & 7);
            half_t* hp0 = &hfrag[wid][0][0][kb][0][0];
            half_t* hp1 = &hfrag[wid][1][0][kb][0][0];
            #pragma unroll
            for (int r = 0; r < 4; ++r) {
                float2 ch0 = lstm_gate(acc0[0][r], acc0[1][r], acc0[2][r], acc0[3][r], c0s[0][jj][r]);
                c0s[0][jj][r] = ch0.x;
                hp0[lb + 8 * r] = (half_t)ch0.y;
                float2 ch1 = lstm_gate(acc1[0][r], acc1[1][r], acc1[2][r], acc1[3][r], c0s[1][jj][r]);
                c0s[1][jj][r] = ch1.x;
                hp1[lb + 8 * r] = (half_t)ch1.y;
            }
        }

        // ------- layer 1 (h1-recurrent MFMAs first: independent of layer-0 gates) -------
        f16x8 q0a0 = *(const f16x8*)&hfrag[wid][0][0][0][lane][0];
        f16x8 q0a1 = *(const f16x8*)&hfrag[wid][0][0][1][lane][0];
        f16x8 q1a0 = *(const f16x8*)&hfrag[wid][1][0][0][lane][0];
        f16x8 q1a1 = *(const f16x8*)&hfrag[wid][1][0][1][lane][0];
        #pragma unroll
        for (int jj = 0; jj < 4; ++jj) {
            f32x4 acc0[4], acc1[4];
            __builtin_amdgcn_s_setprio(1);
            #pragma unroll
            for (int g = 0; g < 4; ++g) {
                const int cb = jj + 4 * g;
                const float bv = b1r[cb];
                f16x8 bi0 = *(const f16x8*)&wlds[1][cb][0][lane][0];
                f16x8 bi1 = *(const f16x8*)&wlds[1][cb][1][lane][0];
                f16x8 bh0 = *(const f16x8*)&wlds[2][cb][0][lane][0];
                f16x8 bh1 = *(const f16x8*)&wlds[2][cb][1][lane][0];
                f32x4 a0 = {bv, bv, bv, bv};
                a0 = MFMA16(q0b0, bh0, a0);     // h1 part first (indep of L0 gates)
                a0 = MFMA16(q0b1, bh1, a0);
                a0 = MFMA16(q0a0, bi0, a0);     // h0 part (dep on L0 gates)
                a0 = MFMA16(q0a1, bi1, a0);
                acc0[g] = a0;
                f32x4 a1 = {bv, bv, bv, bv};
                a1 = MFMA16(q1b0, bh0, a1);
                a1 = MFMA16(q1b1, bh1, a1);
                a1 = MFMA16(q1a0, bi0, a1);
                a1 = MFMA16(q1a1, bi1, a1);
                acc1[g] = a1;
            }
            __builtin_amdgcn_s_setprio(0);
            const int kb = jj >> 1;
            const int lb = (4 * qq + 16 * ((2 * jj + (cc >> 3)) & 3)) * 8 + (cc & 7);
            half_t* hp0 = &hfrag[wid][0][1][kb][0][0];
            half_t* hp1 = &hfrag[wid][1][1][kb][0][0];
            #pragma unroll
            for (int r = 0; r < 4; ++r) {
                float2 ch0 = lstm_gate(acc0[0][r], acc0[1][r], acc0[2][r], acc0[3][r], c1s[0][jj][r]);
                c1s[0][jj][r] = ch0.x;
                hp0[lb + 8 * r] = (half_t)ch0.y;
                float2 ch1 = lstm_gate(acc1[0][r], acc1[1][r], acc1[2][r], acc1[3][r], c1s[1][jj][r]);
                c1s[1][jj][r] = ch1.x;
                hp1[lb + 8 * r] = (half_t)ch1.y;
            }
        }
    }

    // store final h1 A-frags for both tiles
    const int ntiles = (N + 15) >> 4;
    {
        const int tile0 = pair * 2;
        half_t* hout = (half_t*)hws + HOUT_H + (size_t)tile0 * 1024;
        *(f16x8*)&hout[0   + lane * 8] = *(const f16x8*)&hfrag[wid][0][1][0][lane][0];
        *(f16x8*)&hout[512 + lane * 8] = *(const f16x8*)&hfrag[wid][0][1][1][lane][0];
        if (tile0 + 1 < ntiles) {
            half_t* hout1 = (half_t*)hws + HOUT_H + (size_t)(tile0 + 1) * 1024;
            *(f16x8*)&hout1[0   + lane * 8] = *(const f16x8*)&hfrag[wid][1][1][0][lane][0];
            *(f16x8*)&hout1[512 + lane * 8] = *(const f16x8*)&hfrag[wid][1][1][1][lane][0];
        }
    }
}

// ==================== K2: epilogue MLP ====================
__global__ __launch_bounds__(TPB2, 1)
void epi_mlp(const float* __restrict__ xy, const half_t* __restrict__ hws,
             float* __restrict__ out, int ntiles, int N)
{
    __shared__ __align__(16) half_t ef[35840];                  // 70 KB
    __shared__ float biasl[517];
    __shared__ __align__(16) half_t hbuf[8][2][2][64][8];       // 32 KB

    for (int idx = threadIdx.x; idx < 4480; idx += TPB2)
        *(f16x8*)&ef[idx * 8] = *(const f16x8*)&hws[(EPI_H + idx * 8)];
    const float* bg = (const float*)((const char*)hws + BIAS_B);
    for (int i = threadIdx.x; i < 517; i += TPB2) biasl[i] = bg[i];
    __syncthreads();

    const half_t* hout = hws + HOUT_H;
    const int lane = threadIdx.x & 63;
    const int wid  = threadIdx.x >> 6;
    const int cc   = lane & 15;
    const int qq   = lane >> 4;
    const int gw = blockIdx.x * 8 + wid;
    const int nw = gridDim.x * 8;

#define WRITE_ACT(BUF, VALS) do {                                              \
        _Pragma("unroll")                                                      \
        for (int cb = 0; cb < 4; ++cb) {                                       \
            half_t* hp = &hbuf[wid][BUF][cb >> 1][0][0];                       \
            const int lb = (4*qq + 16*((2*cb + (cc>>3)) & 3))*8 + (cc & 7);    \
            _Pragma("unroll")                                                  \
            for (int r = 0; r < 4; ++r) hp[lb + 8*r] = (half_t)(VALS)[cb][r];  \
        }                                                                      \
        asm volatile("" ::: "memory");                                         \
    } while (0)

    #pragma unroll 1
    for (int tile = gw; tile < ntiles; tile += nw) {
        const size_t hob = (size_t)tile * 1024;
        f16x8 e0 = *(const f16x8*)&hout[hob + lane * 8];
        f16x8 e1 = *(const f16x8*)&hout[hob + 512 + lane * 8];

        int s = tile * 16 + cc; if (s >= N) s = N - 1;
        const float fx = xy[2 * s], fy = xy[2 * s + 1];
        F16x8U AF; AF.u[0] = AF.u[1] = AF.u[2] = AF.u[3] = 0;
        if (qq == 0) { AF.h[0] = (half_t)fx; AF.h[1] = (half_t)fy; AF.h[2] = (half_t)1.0f; }

        float zz[4][4];
        #pragma unroll
        for (int cb = 0; cb < 4; ++cb) {
            f32x4 a = {0.f, 0.f, 0.f, 0.f};
            a = MFMA16(e0,   *(const f16x8*)&ef[(EF_FUS + ((cb * 3 + 0) * 64 + lane) * 8)], a);
            a = MFMA16(e1,   *(const f16x8*)&ef[(EF_FUS + ((cb * 3 + 1) * 64 + lane) * 8)], a);
            a = MFMA16(AF.v, *(const f16x8*)&ef[(EF_FUS + ((cb * 3 + 2) * 64 + lane) * 8)], a);
            #pragma unroll
            for (int r = 0; r < 4; ++r) zz[cb][r] = ftanh(a[r]);
        }
        WRITE_ACT(0, zz);
        f16x8 za0 = *(const f16x8*)&hbuf[wid][0][0][lane][0];
        f16x8 za1 = *(const f16x8*)&hbuf[wid][0][1][lane][0];

        #pragma unroll 1
        for (int rb = 0; rb < 3; ++rb) {
            float tt[4][4];
            #pragma unroll
            for (int cb = 0; cb < 4; ++cb) {
                const float bv = biasl[64 + rb * 64 + cb * 16 + cc];
                f32x4 a = {bv, bv, bv, bv};
                a = MFMA16(za0, *(const f16x8*)&ef[(EF_R1 + (((rb * 4 + cb) * 2 + 0) * 64 + lane) * 8)], a);
                a = MFMA16(za1, *(const f16x8*)&ef[(EF_R1 + (((rb * 4 + cb) * 2 + 1) * 64 + lane) * 8)], a);
                #pragma unroll
                for (int r = 0; r < 4; ++r) tt[cb][r] = ftanh(a[r]);
            }
            WRITE_ACT(1, tt);
            f16x8 ta0 = *(const f16x8*)&hbuf[wid][1][0][lane][0];
            f16x8 ta1 = *(const f16x8*)&hbuf[wid][1][1][lane][0];
            #pragma unroll
            for (int cb = 0; cb < 4; ++cb) {
                const float bv = biasl[256 + rb * 64 + cb * 16 + cc];
                f32x4 a = {bv, bv, bv, bv};
                a = MFMA16(ta0, *(const f16x8*)&ef[(EF_R2 + (((rb * 4 + cb) * 2 + 0) * 64 + lane) * 8)], a);
                a = MFMA16(ta1, *(const f16x8*)&ef[(EF_R2 + (((rb * 4 + cb) * 2 + 1) * 64 + lane) * 8)], a);
                #pragma unroll
                for (int r = 0; r < 4; ++r) zz[cb][r] += ftanh(a[r]);
            }
            WRITE_ACT(0, zz);
            za0 = *(const f16x8*)&hbuf[wid][0][0][lane][0];
            za1 = *(const f16x8*)&hbuf[wid][0][1][lane][0];
        }

        float hh[4][4];
        #pragma unroll
        for (int cb = 0; cb < 4; ++cb) {
            const float bv = biasl[448 + cb * 16 + cc];
            f32x4 a = {bv, bv, bv, bv};
            a = MFMA16(za0, *(const f16x8*)&ef[(EF_HW1 + ((cb * 2 + 0) * 64 + lane) * 8)], a);
            a = MFMA16(za1, *(const f16x8*)&ef[(EF_HW1 + ((cb * 2 + 1) * 64 + lane) * 8)], a);
            #pragma unroll
            for (int r = 0; r < 4; ++r) hh[cb][r] = ftanh(a[r]);
        }
        WRITE_ACT(1, hh);
        f16x8 ha0 = *(const f16x8*)&hbuf[wid][1][0][lane][0];
        f16x8 ha1 = *(const f16x8*)&hbuf[wid][1][1][lane][0];

        {
            const float bv = (cc < 5) ? biasl[512 + cc] : 0.0f;
            f32x4 a = {bv, bv, bv, bv};
            a = MFMA16(ha0, *(const f16x8*)&ef[(EF_HW2 + ((0) * 64 + lane) * 8)], a);
            a = MFMA16(ha1, *(const f16x8*)&ef[(EF_HW2 + ((1) * 64 + lane) * 8)], a);
            if (cc < 5) {
                #pragma unroll
                for (int r = 0; r < 4; ++r) {
                    const int row = tile * 16 + 4 * qq + r;
                    if (row < N) out[row * 5 + cc] = a[r];
                }
            }
        }
    }
#undef WRITE_ACT
}

extern "C" void kernel_launch(void* const* d_in, const int* in_sizes, int n_in,
                              void* d_out, int out_size, void* d_ws, size_t ws_size,
                              hipStream_t stream) {
    const float* xy      = (const float*)d_in[0];
    const float* w_ih0   = (const float*)d_in[1];
    const float* w_hh0   = (const float*)d_in[2];
    const float* b0      = (const float*)d_in[3];
    const float* w_ih1   = (const float*)d_in[4];
    const float* w_hh1   = (const float*)d_in[5];
    const float* b1      = (const float*)d_in[6];
    const float* fus_w   = (const float*)d_in[7];
    const float* fus_b   = (const float*)d_in[8];
    const float* res_w1  = (const float*)d_in[9];
    const float* res_b1  = (const float*)d_in[10];
    const float* res_w2  = (const float*)d_in[11];
    const float* res_b2  = (const float*)d_in[12];
    const float* head_w1 = (const float*)d_in[13];
    const float* head_b1 = (const float*)d_in[14];
    const float* head_w2 = (const float*)d_in[15];
    const float* head_b2 = (const float*)d_in[16];

    const int N = in_sizes[0] / 2;
    const int ntiles = (N + 15) / 16;
    const int npairs = (ntiles + 1) / 2;
    half_t* hws = (half_t*)d_ws;

    pack_weights<<<dim3(46), dim3(256), 0, stream>>>(
        w_ih0, w_hh0, b0, w_ih1, w_hh1, b1,
        fus_w, fus_b, res_w1, res_b1, res_w2, res_b2,
        head_w1, head_b1, head_w2, head_b2, hws);

    const int grid1 = (npairs + WAVES - 1) / WAVES;
    lstm_core<<<dim3(grid1), dim3(TPB), 0, stream>>>(xy, hws, N);

    epi_mlp<<<dim3(256), dim3(TPB2), 0, stream>>>(xy, hws, (float*)d_out, ntiles, N);
}

// Round 11
// 450.691 us; speedup vs baseline: 1.3828x; 1.1752x over previous
//
#include <hip/hip_runtime.h>
#include <math.h>

#define PI_F 3.14159265358979323846f
#define WAVES 8
#define TPB (WAVES*64)
#define TPB2 512

// gate pre-activation scales folded into weights at pack time:
// i,f,o rows: -log2(e); g rows: -2*log2(e)
#define GS_IFO (-1.4426950408889634f)
#define GS_G   (-2.8853900817779268f)

typedef _Float16 half_t;
typedef __attribute__((ext_vector_type(8))) _Float16 f16x8;
typedef __attribute__((ext_vector_type(4))) float f32x4;

union F16x8U { f16x8 v; unsigned int u[4]; half_t h[8]; };

__device__ __forceinline__ float frcp(float x)  { return __builtin_amdgcn_rcpf(x); }
__device__ __forceinline__ float fexp2(float x) { return __builtin_amdgcn_exp2f(x); }
__device__ __forceinline__ float ftanh(float x) { return 1.0f - 2.0f * frcp(1.0f + __expf(2.0f * x)); }

// gate with PRE-SCALED inputs: ai,af,ao = -log2e*orig ; ag = -2log2e*orig
__device__ __forceinline__ float2 lstm_gate(float ai, float af, float ag, float ao, float cold) {
    float ui = fexp2(ai);
    float uf = fexp2(af);
    float ug = fexp2(ag);
    float uo = fexp2(ao);
    float ig = (1.0f - ug) * frcp((1.0f + ui) * (1.0f + ug));   // sigmoid(i)*tanh(g)
    float ff = frcp(1.0f + uf);                                  // sigmoid(f)
    float cv = fmaf(ff, cold, ig);
    float uc = fexp2(GS_G * cv);
    float hh = (1.0f - uc) * frcp((1.0f + uo) * (1.0f + uc));   // sigmoid(o)*tanh(c)
    return make_float2(cv, hh);
}

#define MFMA16(a,b,c) __builtin_amdgcn_mfma_f32_16x16x32_f16((a),(b),(c),0,0,0)

// ---- d_ws layout (byte offsets) ----
#define AUG_B   98304
#define B1_B    99328
#define EPI_H   50176      // half index
#define BIAS_B  172032
#define HOUT_H  88064      // half index
#define EF_FUS  0
#define EF_R1   6144
#define EF_R2   18432
#define EF_HW1  30720
#define EF_HW2  34816

// ==================== K0: pack all weights ====================
__global__ void pack_weights(const float* __restrict__ w_ih0, const float* __restrict__ w_hh0, const float* __restrict__ b0,
                             const float* __restrict__ w_ih1, const float* __restrict__ w_hh1, const float* __restrict__ b1,
                             const float* __restrict__ fus_w, const float* __restrict__ fus_b,
                             const float* __restrict__ res_w1, const float* __restrict__ res_b1,
                             const float* __restrict__ res_w2, const float* __restrict__ res_b2,
                             const float* __restrict__ head_w1, const float* __restrict__ head_b1,
                             const float* __restrict__ head_w2, const float* __restrict__ head_b2,
                             half_t* __restrict__ hws)
{
    int id = blockIdx.x * blockDim.x + threadIdx.x;

    if (id < 6144) {                       // recurrent B-frags, gate-scaled
        int ln = id & 63, rest = id >> 6;
        int kb = rest & 1, cb = (rest >> 1) & 15, mat = rest >> 5;
        const float* W = (mat == 0) ? w_hh0 : ((mat == 1) ? w_ih1 : w_hh1);
        const int gate = cb >> 2;
        const float sc = (gate == 2) ? GS_G : GS_IFO;
        const float* src = W + (cb * 16 + (ln & 15)) * 64 + kb * 32 + (ln >> 4) * 8;
        F16x8U t;
        #pragma unroll
        for (int i = 0; i < 8; ++i) t.h[i] = (half_t)(sc * src[i]);
        *(f16x8*)&hws[id * 8] = t.v;
        return;
    }
    id -= 6144;
    if (id < 256) {                        // aug0 table: {w_ih0[j], b0[j]} gate-scaled
        const int gate = id >> 6;
        const float sc = (gate == 2) ? GS_G : GS_IFO;
        F16x8U t; t.u[0] = 0;
        t.h[0] = (half_t)(sc * w_ih0[id]);
        t.h[1] = (half_t)(sc * b0[id]);
        ((unsigned int*)((char*)hws + AUG_B))[id] = t.u[0];
        return;
    }
    id -= 256;
    if (id < 256) {                        // b1 fp32, gate-scaled
        const int gate = id >> 6;
        const float sc = (gate == 2) ? GS_G : GS_IFO;
        ((float*)((char*)hws + B1_B))[id] = sc * b1[id];
        return;
    }
    id -= 256;
    if (id < 768) {                        // fus frags (unscaled)
        int ln = id & 63, rest = id >> 6;
        int kb = rest % 3, cb = rest / 3;
        int col = cb * 16 + (ln & 15), q = ln >> 4;
        F16x8U t; t.u[0] = t.u[1] = t.u[2] = t.u[3] = 0;
        if (kb < 2) {
            #pragma unroll
            for (int i = 0; i < 8; ++i) t.h[i] = (half_t)fus_w[col * 66 + kb * 32 + q * 8 + i];
        } else if (q == 0) {
            t.h[0] = (half_t)fus_w[col * 66 + 64];
            t.h[1] = (half_t)fus_w[col * 66 + 65];
            t.h[2] = (half_t)fus_b[col];
        }
        *(f16x8*)&hws[(EPI_H + EF_FUS + id * 8)] = t.v;
        return;
    }
    id -= 768;
    if (id < 1536) {                       // res1 frags
        int ln = id & 63, rest = id >> 6;
        int kb = rest & 1, cb = (rest >> 1) & 3, rb = rest >> 3;
        int col = cb * 16 + (ln & 15), q = ln >> 4;
        F16x8U t;
        #pragma unroll
        for (int i = 0; i < 8; ++i) t.h[i] = (half_t)res_w1[rb * 4096 + col * 64 + kb * 32 + q * 8 + i];
        *(f16x8*)&hws[(EPI_H + EF_R1 + id * 8)] = t.v;
        return;
    }
    id -= 1536;
    if (id < 1536) {                       // res2 frags
        int ln = id & 63, rest = id >> 6;
        int kb = rest & 1, cb = (rest >> 1) & 3, rb = rest >> 3;
        int col = cb * 16 + (ln & 15), q = ln >> 4;
        F16x8U t;
        #pragma unroll
        for (int i = 0; i < 8; ++i) t.h[i] = (half_t)res_w2[rb * 4096 + col * 64 + kb * 32 + q * 8 + i];
        *(f16x8*)&hws[(EPI_H + EF_R2 + id * 8)] = t.v;
        return;
    }
    id -= 1536;
    if (id < 512) {                        // head_w1 frags
        int ln = id & 63, rest = id >> 6;
        int kb = rest & 1, cb = rest >> 1;
        int col = cb * 16 + (ln & 15), q = ln >> 4;
        F16x8U t;
        #pragma unroll
        for (int i = 0; i < 8; ++i) t.h[i] = (half_t)head_w1[col * 64 + kb * 32 + q * 8 + i];
        *(f16x8*)&hws[(EPI_H + EF_HW1 + id * 8)] = t.v;
        return;
    }
    id -= 512;
    if (id < 128) {                        // head_w2 frags
        int ln = id & 63, kb = id >> 6;
        int col = ln & 15, q = ln >> 4;
        F16x8U t; t.u[0] = t.u[1] = t.u[2] = t.u[3] = 0;
        if (col < 5) {
            #pragma unroll
            for (int i = 0; i < 8; ++i) t.h[i] = (half_t)head_w2[col * 64 + kb * 32 + q * 8 + i];
        }
        *(f16x8*)&hws[(EPI_H + EF_HW2 + id * 8)] = t.v;
        return;
    }
    id -= 128;
    if (id < 517) {                        // biases fp32 (unscaled, epilogue)
        float v;
        if      (id < 64)  v = fus_b[id];
        else if (id < 256) v = res_b1[id - 64];
        else if (id < 448) v = res_b2[id - 256];
        else if (id < 512) v = head_b1[id - 448];
        else               v = head_b2[id - 512];
        ((float*)((char*)hws + BIAS_B))[id] = v;
        return;
    }
}

// ==================== K1: LSTM main loop (2 tiles / wave) — round-8 champion ====================
// launch_bounds(512, 2). LDS = 160 KiB exactly (1 block/CU, 8 waves).
// HARD CONSTRAINT (rounds 3/5/9/10): peak live VGPRs sits exactly at the 128 tier;
// any change extending a live range across a layer phase (hoisted frag reads,
// reg-resident weights, fence removal) spills -> FETCH/WRITE blow-up. Do not touch.
__global__ __launch_bounds__(TPB, 2)
void lstm_core(const float* __restrict__ xy, const half_t* __restrict__ hws, int N)
{
    __shared__ __align__(16) half_t wlds[3][16][2][64][8];          // 98304 B
    __shared__ __align__(16) half_t hfrag[WAVES][2][2][2][64][8];   // 65536 B -> 163840 total

    const int lane = threadIdx.x & 63;
    const int wid  = threadIdx.x >> 6;
    const int cc   = lane & 15;
    const int qq   = lane >> 4;

    // stage pre-packed weights (flat vector copy)
    for (int idx = threadIdx.x; idx < 6144; idx += TPB)
        *(f16x8*)&((half_t*)wlds)[idx * 8] = *(const f16x8*)&hws[idx * 8];
    __syncthreads();

    // loop-invariant per-lane tables in VGPRs (L2-hit loads, once)
    unsigned int augr[16];
    float b1r[16];
    {
        const unsigned int* at = (const unsigned int*)((const char*)hws + AUG_B);
        const float* bt = (const float*)((const char*)hws + B1_B);
        #pragma unroll
        for (int cb = 0; cb < 16; ++cb) {
            augr[cb] = (qq == 0) ? at[cb * 16 + cc] : 0u;
            b1r[cb]  = bt[cb * 16 + cc];
        }
    }

    const int pair = blockIdx.x * WAVES + wid;    // each wave: tiles 2p, 2p+1 (32 samples)
    const int S0 = pair * 32;
    if (S0 >= N) return;

    int si0 = S0 + cc;      if (si0 >= N) si0 = N - 1;
    int si1 = S0 + 16 + cc; if (si1 >= N) si1 = N - 1;
    const float fx0 = xy[2 * si0], fy0 = xy[2 * si0 + 1];
    const float fx1 = xy[2 * si1], fy1 = xy[2 * si1 + 1];
    float feat0[9], feat1[9];
    feat0[0] = fx0; feat0[1] = fy0; feat0[2] = fx0 * fx0; feat0[3] = fy0 * fy0; feat0[4] = fx0 * fy0;
    feat0[5] = sinf(PI_F * fx0); feat0[6] = cosf(PI_F * fx0);
    feat0[7] = sinf(PI_F * fy0); feat0[8] = cosf(PI_F * fy0);
    feat1[0] = fx1; feat1[1] = fy1; feat1[2] = fx1 * fx1; feat1[3] = fy1 * fy1; feat1[4] = fx1 * fy1;
    feat1[5] = sinf(PI_F * fx1); feat1[6] = cosf(PI_F * fx1);
    feat1[7] = sinf(PI_F * fy1); feat1[8] = cosf(PI_F * fy1);

    {
        F16x8U Z; Z.u[0] = Z.u[1] = Z.u[2] = Z.u[3] = 0;
        #pragma unroll
        for (int p = 0; p < 2; ++p)
            #pragma unroll
            for (int b = 0; b < 2; ++b)
                #pragma unroll
                for (int kb = 0; kb < 2; ++kb)
                    *(f16x8*)&hfrag[wid][p][b][kb][lane][0] = Z.v;
    }
    float c0s[2][4][4], c1s[2][4][4];
    #pragma unroll
    for (int p = 0; p < 2; ++p)
        #pragma unroll
        for (int a = 0; a < 4; ++a)
            #pragma unroll
            for (int b = 0; b < 4; ++b) { c0s[p][a][b] = 0.0f; c1s[p][a][b] = 0.0f; }

    asm volatile("" ::: "memory");

    #pragma unroll 1
    for (int t = 0; t < 9; ++t) {
        float ftv0, ftv1;
        switch (t) {
            case 0: ftv0 = feat0[0]; ftv1 = feat1[0]; break;
            case 1: ftv0 = feat0[1]; ftv1 = feat1[1]; break;
            case 2: ftv0 = feat0[2]; ftv1 = feat1[2]; break;
            case 3: ftv0 = feat0[3]; ftv1 = feat1[3]; break;
            case 4: ftv0 = feat0[4]; ftv1 = feat1[4]; break;
            case 5: ftv0 = feat0[5]; ftv1 = feat1[5]; break;
            case 6: ftv0 = feat0[6]; ftv1 = feat1[6]; break;
            case 7: ftv0 = feat0[7]; ftv1 = feat1[7]; break;
            default: ftv0 = feat0[8]; ftv1 = feat1[8]; break;
        }
        F16x8U AG0, AG1;
        AG0.u[0] = AG0.u[1] = AG0.u[2] = AG0.u[3] = 0;
        AG1.u[0] = AG1.u[1] = AG1.u[2] = AG1.u[3] = 0;
        if (qq == 0) {
            AG0.h[0] = (half_t)ftv0; AG0.h[1] = (half_t)1.0f;
            AG1.h[0] = (half_t)ftv1; AG1.h[1] = (half_t)1.0f;
        }

        // ------- layer 0 (both tiles share every B-frag read) -------
        f16x8 p0a0 = *(const f16x8*)&hfrag[wid][0][0][0][lane][0];
        f16x8 p0a1 = *(const f16x8*)&hfrag[wid][0][0][1][lane][0];
        f16x8 p1a0 = *(const f16x8*)&hfrag[wid][1][0][0][lane][0];
        f16x8 p1a1 = *(const f16x8*)&hfrag[wid][1][0][1][lane][0];
        #pragma unroll
        for (int jj = 0; jj < 4; ++jj) {
            f32x4 acc0[4], acc1[4];
            #pragma unroll
            for (int g = 0; g < 4; ++g) {
                const int cb = jj + 4 * g;
                F16x8U BA; BA.u[0] = augr[cb]; BA.u[1] = 0; BA.u[2] = 0; BA.u[3] = 0;
                f16x8 bf0 = *(const f16x8*)&wlds[0][cb][0][lane][0];
                f16x8 bf1 = *(const f16x8*)&wlds[0][cb][1][lane][0];
                f32x4 a0 = {0.f, 0.f, 0.f, 0.f};
                a0 = MFMA16(AG0.v, BA.v, a0);
                a0 = MFMA16(p0a0, bf0, a0);
                a0 = MFMA16(p0a1, bf1, a0);
                acc0[g] = a0;
                f32x4 a1 = {0.f, 0.f, 0.f, 0.f};
                a1 = MFMA16(AG1.v, BA.v, a1);
                a1 = MFMA16(p1a0, bf0, a1);
                a1 = MFMA16(p1a1, bf1, a1);
                acc1[g] = a1;
            }
            const int kb = jj >> 1;
            const int lb = (4 * qq + 16 * ((2 * jj + (cc >> 3)) & 3)) * 8 + (cc & 7);
            half_t* hp0 = &hfrag[wid][0][0][kb][0][0];
            half_t* hp1 = &hfrag[wid][1][0][kb][0][0];
            #pragma unroll
            for (int r = 0; r < 4; ++r) {
                float2 ch0 = lstm_gate(acc0[0][r], acc0[1][r], acc0[2][r], acc0[3][r], c0s[0][jj][r]);
                c0s[0][jj][r] = ch0.x;
                hp0[lb + 8 * r] = (half_t)ch0.y;
                float2 ch1 = lstm_gate(acc1[0][r], acc1[1][r], acc1[2][r], acc1[3][r], c0s[1][jj][r]);
                c0s[1][jj][r] = ch1.x;
                hp1[lb + 8 * r] = (half_t)ch1.y;
            }
        }
        asm volatile("" ::: "memory");

        // ------- layer 1 -------
        f16x8 q0a0 = *(const f16x8*)&hfrag[wid][0][0][0][lane][0];
        f16x8 q0a1 = *(const f16x8*)&hfrag[wid][0][0][1][lane][0];
        f16x8 q0b0 = *(const f16x8*)&hfrag[wid][0][1][0][lane][0];
        f16x8 q0b1 = *(const f16x8*)&hfrag[wid][0][1][1][lane][0];
        f16x8 q1a0 = *(const f16x8*)&hfrag[wid][1][0][0][lane][0];
        f16x8 q1a1 = *(const f16x8*)&hfrag[wid][1][0][1][lane][0];
        f16x8 q1b0 = *(const f16x8*)&hfrag[wid][1][1][0][lane][0];
        f16x8 q1b1 = *(const f16x8*)&hfrag[wid][1][1][1][lane][0];
        #pragma unroll
        for (int jj = 0; jj < 4; ++jj) {
            f32x4 acc0[4], acc1[4];
            #pragma unroll
            for (int g = 0; g < 4; ++g) {
                const int cb = jj + 4 * g;
                const float bv = b1r[cb];
                f16x8 bi0 = *(const f16x8*)&wlds[1][cb][0][lane][0];
                f16x8 bi1 = *(const f16x8*)&wlds[1][cb][1][lane][0];
                f16x8 bh0 = *(const f16x8*)&wlds[2][cb][0][lane][0];
                f16x8 bh1 = *(const f16x8*)&wlds[2][cb][1][lane][0];
                f32x4 a0 = {bv, bv, bv, bv};
                a0 = MFMA16(q0a0, bi0, a0);
                a0 = MFMA16(q0a1, bi1, a0);
                a0 = MFMA16(q0b0, bh0, a0);
                a0 = MFMA16(q0b1, bh1, a0);
                acc0[g] = a0;
                f32x4 a1 = {bv, bv, bv, bv};
                a1 = MFMA16(q1a0, bi0, a1);
                a1 = MFMA16(q1a1, bi1, a1);
                a1 = MFMA16(q1b0, bh0, a1);
                a1 = MFMA16(q1b1, bh1, a1);
                acc1[g] = a1;
            }
            const int kb = jj >> 1;
            const int lb = (4 * qq + 16 * ((2 * jj + (cc >> 3)) & 3)) * 8 + (cc & 7);
            half_t* hp0 = &hfrag[wid][0][1][kb][0][0];
            half_t* hp1 = &hfrag[wid][1][1][kb][0][0];
            #pragma unroll
            for (int r = 0; r < 4; ++r) {
                float2 ch0 = lstm_gate(acc0[0][r], acc0[1][r], acc0[2][r], acc0[3][r], c1s[0][jj][r]);
                c1s[0][jj][r] = ch0.x;
                hp0[lb + 8 * r] = (half_t)ch0.y;
                float2 ch1 = lstm_gate(acc1[0][r], acc1[1][r], acc1[2][r], acc1[3][r], c1s[1][jj][r]);
                c1s[1][jj][r] = ch1.x;
                hp1[lb + 8 * r] = (half_t)ch1.y;
            }
        }
        asm volatile("" ::: "memory");
    }

    // store final h1 A-frags for both tiles
    const int ntiles = (N + 15) >> 4;
    {
        const int tile0 = pair * 2;
        half_t* hout = (half_t*)hws + HOUT_H + (size_t)tile0 * 1024;
        *(f16x8*)&hout[0   + lane * 8] = *(const f16x8*)&hfrag[wid][0][1][0][lane][0];
        *(f16x8*)&hout[512 + lane * 8] = *(const f16x8*)&hfrag[wid][0][1][1][lane][0];
        if (tile0 + 1 < ntiles) {
            half_t* hout1 = (half_t*)hws + HOUT_H + (size_t)(tile0 + 1) * 1024;
            *(f16x8*)&hout1[0   + lane * 8] = *(const f16x8*)&hfrag[wid][1][1][0][lane][0];
            *(f16x8*)&hout1[512 + lane * 8] = *(const f16x8*)&hfrag[wid][1][1][1][lane][0];
        }
    }
}

// ==================== K2: epilogue MLP ====================
__global__ __launch_bounds__(TPB2, 1)
void epi_mlp(const float* __restrict__ xy, const half_t* __restrict__ hws,
             float* __restrict__ out, int ntiles, int N)
{
    __shared__ __align__(16) half_t ef[35840];                  // 70 KB
    __shared__ float biasl[517];
    __shared__ __align__(16) half_t hbuf[8][2][2][64][8];       // 32 KB

    for (int idx = threadIdx.x; idx < 4480; idx += TPB2)
        *(f16x8*)&ef[idx * 8] = *(const f16x8*)&hws[(EPI_H + idx * 8)];
    const float* bg = (const float*)((const char*)hws + BIAS_B);
    for (int i = threadIdx.x; i < 517; i += TPB2) biasl[i] = bg[i];
    __syncthreads();

    const half_t* hout = hws + HOUT_H;
    const int lane = threadIdx.x & 63;
    const int wid  = threadIdx.x >> 6;
    const int cc   = lane & 15;
    const int qq   = lane >> 4;
    const int gw = blockIdx.x * 8 + wid;
    const int nw = gridDim.x * 8;

#define WRITE_ACT(BUF, VALS) do {                                              \
        _Pragma("unroll")                                                      \
        for (int cb = 0; cb < 4; ++cb) {                                       \
            half_t* hp = &hbuf[wid][BUF][cb >> 1][0][0];                       \
            const int lb = (4*qq + 16*((2*cb + (cc>>3)) & 3))*8 + (cc & 7);    \
            _Pragma("unroll")                                                  \
            for (int r = 0; r < 4; ++r) hp[lb + 8*r] = (half_t)(VALS)[cb][r];  \
        }                                                                      \
        asm volatile("" ::: "memory");                                         \
    } while (0)

    #pragma unroll 1
    for (int tile = gw; tile < ntiles; tile += nw) {
        const size_t hob = (size_t)tile * 1024;
        f16x8 e0 = *(const f16x8*)&hout[hob + lane * 8];
        f16x8 e1 = *(const f16x8*)&hout[hob + 512 + lane * 8];

        int s = tile * 16 + cc; if (s >= N) s = N - 1;
        const float fx = xy[2 * s], fy = xy[2 * s + 1];
        F16x8U AF; AF.u[0] = AF.u[1] = AF.u[2] = AF.u[3] = 0;
        if (qq == 0) { AF.h[0] = (half_t)fx; AF.h[1] = (half_t)fy; AF.h[2] = (half_t)1.0f; }

        float zz[4][4];
        #pragma unroll
        for (int cb = 0; cb < 4; ++cb) {
            f32x4 a = {0.f, 0.f, 0.f, 0.f};
            a = MFMA16(e0,   *(const f16x8*)&ef[(EF_FUS + ((cb * 3 + 0) * 64 + lane) * 8)], a);
            a = MFMA16(e1,   *(const f16x8*)&ef[(EF_FUS + ((cb * 3 + 1) * 64 + lane) * 8)], a);
            a = MFMA16(AF.v, *(const f16x8*)&ef[(EF_FUS + ((cb * 3 + 2) * 64 + lane) * 8)], a);
            #pragma unroll
            for (int r = 0; r < 4; ++r) zz[cb][r] = ftanh(a[r]);
        }
        WRITE_ACT(0, zz);
        f16x8 za0 = *(const f16x8*)&hbuf[wid][0][0][lane][0];
        f16x8 za1 = *(const f16x8*)&hbuf[wid][0][1][lane][0];

        #pragma unroll 1
        for (int rb = 0; rb < 3; ++rb) {
            float tt[4][4];
            #pragma unroll
            for (int cb = 0; cb < 4; ++cb) {
                const float bv = biasl[64 + rb * 64 + cb * 16 + cc];
                f32x4 a = {bv, bv, bv, bv};
                a = MFMA16(za0, *(const f16x8*)&ef[(EF_R1 + (((rb * 4 + cb) * 2 + 0) * 64 + lane) * 8)], a);
                a = MFMA16(za1, *(const f16x8*)&ef[(EF_R1 + (((rb * 4 + cb) * 2 + 1) * 64 + lane) * 8)], a);
                #pragma unroll
                for (int r = 0; r < 4; ++r) tt[cb][r] = ftanh(a[r]);
            }
            WRITE_ACT(1, tt);
            f16x8 ta0 = *(const f16x8*)&hbuf[wid][1][0][lane][0];
            f16x8 ta1 = *(const f16x8*)&hbuf[wid][1][1][lane][0];
            #pragma unroll
            for (int cb = 0; cb < 4; ++cb) {
                const float bv = biasl[256 + rb * 64 + cb * 16 + cc];
                f32x4 a = {bv, bv, bv, bv};
                a = MFMA16(ta0, *(const f16x8*)&ef[(EF_R2 + (((rb * 4 + cb) * 2 + 0) * 64 + lane) * 8)], a);
                a = MFMA16(ta1, *(const f16x8*)&ef[(EF_R2 + (((rb * 4 + cb) * 2 + 1) * 64 + lane) * 8)], a);
                #pragma unroll
                for (int r = 0; r < 4; ++r) zz[cb][r] += ftanh(a[r]);
            }
            WRITE_ACT(0, zz);
            za0 = *(const f16x8*)&hbuf[wid][0][0][lane][0];
            za1 = *(const f16x8*)&hbuf[wid][0][1][lane][0];
        }

        float hh[4][4];
        #pragma unroll
        for (int cb = 0; cb < 4; ++cb) {
            const float bv = biasl[448 + cb * 16 + cc];
            f32x4 a = {bv, bv, bv, bv};
            a = MFMA16(za0, *(const f16x8*)&ef[(EF_HW1 + ((cb * 2 + 0) * 64 + lane) * 8)], a);
            a = MFMA16(za1, *(const f16x8*)&ef[(EF_HW1 + ((cb * 2 + 1) * 64 + lane) * 8)], a);
            #pragma unroll
            for (int r = 0; r < 4; ++r) hh[cb][r] = ftanh(a[r]);
        }
        WRITE_ACT(1, hh);
        f16x8 ha0 = *(const f16x8*)&hbuf[wid][1][0][lane][0];
        f16x8 ha1 = *(const f16x8*)&hbuf[wid][1][1][lane][0];

        {
            const float bv = (cc < 5) ? biasl[512 + cc] : 0.0f;
            f32x4 a = {bv, bv, bv, bv};
            a = MFMA16(ha0, *(const f16x8*)&ef[(EF_HW2 + ((0) * 64 + lane) * 8)], a);
            a = MFMA16(ha1, *(const f16x8*)&ef[(EF_HW2 + ((1) * 64 + lane) * 8)], a);
            if (cc < 5) {
                #pragma unroll
                for (int r = 0; r < 4; ++r) {
                    const int row = tile * 16 + 4 * qq + r;
                    if (row < N) out[row * 5 + cc] = a[r];
                }
            }
        }
    }
#undef WRITE_ACT
}

extern "C" void kernel_launch(void* const* d_in, const int* in_sizes, int n_in,
                              void* d_out, int out_size, void* d_ws, size_t ws_size,
                              hipStream_t stream) {
    const float* xy      = (const float*)d_in[0];
    const float* w_ih0   = (const float*)d_in[1];
    const float* w_hh0   = (const float*)d_in[2];
    const float* b0      = (const float*)d_in[3];
    const float* w_ih1   = (const float*)d_in[4];
    const float* w_hh1   = (const float*)d_in[5];
    const float* b1      = (const float*)d_in[6];
    const float* fus_w   = (const float*)d_in[7];
    const float* fus_b   = (const float*)d_in[8];
    const float* res_w1  = (const float*)d_in[9];
    const float* res_b1  = (const float*)d_in[10];
    const float* res_w2  = (const float*)d_in[11];
    const float* res_b2  = (const float*)d_in[12];
    const float* head_w1 = (const float*)d_in[13];
    const float* head_b1 = (const float*)d_in[14];
    const float* head_w2 = (const float*)d_in[15];
    const float* head_b2 = (const float*)d_in[16];

    const int N = in_sizes[0] / 2;
    const int ntiles = (N + 15) / 16;
    const int npairs = (ntiles + 1) / 2;
    half_t* hws = (half_t*)d_ws;

    pack_weights<<<dim3(46), dim3(256), 0, stream>>>(
        w_ih0, w_hh0, b0, w_ih1, w_hh1, b1,
        fus_w, fus_b, res_w1, res_b1, res_w2, res_b2,
        head_w1, head_b1, head_w2, head_b2, hws);

    const int grid1 = (npairs + WAVES - 1) / WAVES;
    lstm_core<<<dim3(grid1), dim3(TPB), 0, stream>>>(xy, hws, N);

    epi_mlp<<<dim3(256), dim3(TPB2), 0, stream>>>(xy, hws, (float*)d_out, ntiles, N);
}